// Round 19
// baseline (76.668 us; speedup 1.0000x reference)
//
#include <hip/hip_runtime.h>
#include <math.h>

#define DD 768
#define NN 64
#define SS 512
#define BB 4
#define BSD (BB * SS * DD)

__device__ __forceinline__ float sigmf(float v) { return 1.0f / (1.0f + expf(-v)); }

// ---- DPP add helper (bound_ctrl=0-fill) ----
template <int CTRL>
__device__ __forceinline__ float dppadd(float v) {
    int s = __builtin_amdgcn_update_dpp(0, __float_as_int(v), CTRL, 0xF, 0xF, true);
    return v + __int_as_float(s);
}
__device__ __forceinline__ float row_sum15(float v) {
    v = dppadd<0x111>(v);
    v = dppadd<0x112>(v);
    v = dppadd<0x114>(v);
    v = dppadd<0x118>(v);
    return v;
}
__device__ __forceinline__ float wave_sum63(float v) {
    v = row_sum15(v);
    v = dppadd<0x142>(v);
    v = dppadd<0x143>(v);
    return v;
}

// async global->LDS, 16B per lane, dst is WAVE-UNIFORM base (HW adds lane*16)
typedef const __attribute__((address_space(1))) void* gas_ptr;
typedef __attribute__((address_space(3))) void* las_ptr;
#define GLL16(SRC, DST) \
    __builtin_amdgcn_global_load_lds((gas_ptr)(SRC), (las_ptr)(DST), 16, 0, 0)

// ---- fused prep (blocks 0..11) + x-transpose (blocks 12..395) ----
__global__ __launch_bounds__(256) void prep_xpose_kernel(const float* __restrict__ Braw,
                                                         const float* __restrict__ graw,
                                                         const float* __restrict__ x,
                                                         float* __restrict__ BwT,
                                                         float* __restrict__ gamma_s,
                                                         float* __restrict__ xT) {
    __shared__ float tile[64][65];
    int tx = threadIdx.x & 63;
    int tq = threadIdx.x >> 6;  // 0..3
    if (blockIdx.x < 12) {
        int d0 = blockIdx.x * 64;
#pragma unroll
        for (int i = 0; i < 16; ++i) {
            int n = tq + i * 4;
            tile[n][tx] = sigmf(Braw[n * DD + d0 + tx]);
        }
        __syncthreads();
#pragma unroll
        for (int i = 0; i < 16; ++i) {
            int dl = tq + i * 4;
            BwT[(d0 + dl) * NN + tx] = tile[tx][dl];
        }
        int gi = blockIdx.x * 256 + threadIdx.x;
        if (gi < DD) gamma_s[gi] = sigmf(graw[gi]);
    } else {
        int bidx = blockIdx.x - 12;
        int b  = bidx / 96;
        int r  = bidx - b * 96;
        int t0 = (r / 12) * 64;
        int d0 = (r % 12) * 64;
#pragma unroll
        for (int i = 0; i < 16; ++i) {
            int t = tq + i * 4;
            tile[t][tx] = x[((size_t)b * SS + t0 + t) * DD + d0 + tx];
        }
        __syncthreads();
#pragma unroll
        for (int i = 0; i < 16; ++i) {
            int dl = tq + i * 4;
            xT[((size_t)b * DD + d0 + dl) * SS + t0 + tx] = tile[tx][dl];
        }
    }
}

// ---- phase 1 (R14-proven core): LDS-staged BwT; store TILED as
// inpT[b][t>>3][t&7][n] -> scan's global_load_lds deposits a ready [8][64] slab.
__global__ __launch_bounds__(256, 2) void inp_kernel(const float* __restrict__ x,
                                                     const float* __restrict__ BwT,
                                                     float* __restrict__ inp) {
    int w    = threadIdx.x >> 6;
    int lane = threadIdx.x & 63;
    int g = lane >> 4;
    int q = lane & 15;
    int r = blockIdx.x * 4 + w;
    const float*  xr  = x + (size_t)r * DD;
    const float4* bwg = (const float4*)BwT;

    __shared__ float4 bwlds[2][1024];

#pragma unroll
    for (int k = 0; k < 4; ++k)
        bwlds[0][threadIdx.x + k * 256] = bwg[threadIdx.x + k * 256];
    __syncthreads();

    float4 acc = {0.f, 0.f, 0.f, 0.f};
    for (int c = 0; c < 12; ++c) {
        int cur = c & 1;
        float4 s0, s1, s2, s3;
        if (c < 11) {
            int base = (c + 1) * 1024 + threadIdx.x;
            s0 = bwg[base];
            s1 = bwg[base + 256];
            s2 = bwg[base + 512];
            s3 = bwg[base + 768];
        }
        int d0 = c * 64;
#pragma unroll
        for (int jj = 0; jj < 4; ++jj) {
            int dbase = jj * 16 + g;
            float x0 = xr[d0 + dbase + 0];
            float x1 = xr[d0 + dbase + 4];
            float x2 = xr[d0 + dbase + 8];
            float x3 = xr[d0 + dbase + 12];
            float4 w0 = bwlds[cur][(dbase + 0) * 16 + q];
            float4 w1 = bwlds[cur][(dbase + 4) * 16 + q];
            float4 w2 = bwlds[cur][(dbase + 8) * 16 + q];
            float4 w3 = bwlds[cur][(dbase + 12) * 16 + q];
#define IFMA(W, X)                       \
    acc.x = fmaf(X, W.x, acc.x);         \
    acc.y = fmaf(X, W.y, acc.y);         \
    acc.z = fmaf(X, W.z, acc.z);         \
    acc.w = fmaf(X, W.w, acc.w);
            IFMA(w0, x0) IFMA(w1, x1) IFMA(w2, x2) IFMA(w3, x3)
        }
        if (c < 11) {
            int nb = cur ^ 1;
            bwlds[nb][threadIdx.x]       = s0;
            bwlds[nb][threadIdx.x + 256] = s1;
            bwlds[nb][threadIdx.x + 512] = s2;
            bwlds[nb][threadIdx.x + 768] = s3;
        }
        __syncthreads();
    }

#pragma unroll
    for (int off = 16; off <= 32; off <<= 1) {
        acc.x += __shfl_xor(acc.x, off, 64);
        acc.y += __shfl_xor(acc.y, off, 64);
        acc.z += __shfl_xor(acc.z, off, 64);
        acc.w += __shfl_xor(acc.w, off, 64);
    }
    if (lane < 16) {
        int bb = r >> 9;
        int tt = r & 511;
        // (b,t,n) -> inp[(((b*64 + t>>3)*8) + (t&7))*64 + n]
        float* dst = inp + (((size_t)bb * 64 + (tt >> 3)) * 8 + (tt & 7)) * 64;
        ((float4*)dst)[q] = acc;   // n = 4q..4q+3, 256B contiguous per row
    }
}

// ---- phase 2: scan v14. Wave = one d x 64 n. ip stream via global_load_lds
// (no dest regs -> nothing for the compiler to sink), 4-slab ring, 2-chunk
// lead, manual counted s_waitcnt vmcnt(4). xt preloaded to LDS (vmem count
// in loop = exactly 2 GLL/phase). Reduce delayed 1 chunk (kills write->read
// turnaround). y buffered in LDS, written out once at the end.
__global__ __launch_bounds__(256) void scan_kernel(const float* __restrict__ xT,
                                                   const float* __restrict__ Araw,
                                                   const float* __restrict__ Craw,
                                                   const float* __restrict__ inpT,
                                                   float* __restrict__ Y,
                                                   float* __restrict__ hfin) {
    int w    = threadIdx.x >> 6;        // wave in block = d-sub
    int lane = threadIdx.x & 63;        // n
    int gb = blockIdx.x;                // 0..767
    int b  = gb / 192;
    int dg = gb - b * 192;
    int d  = dg * 4 + w;

    float a = sigmf(Araw[(size_t)d * NN + lane]);
    float c = sigmf(Craw[(size_t)d * NN + lane]);

    const float* ipb   = inpT + (size_t)b * 64 * 512;          // [chunk][8][64]
    const float* xtrow = xT + ((size_t)b * DD + d) * SS;       // 512 floats
    float*       y_d   = Y + (size_t)(b * SS) * DD + d;

    __shared__ float ip[4][4][8][64];   // [wave][slab][step][n] = 32 KiB
    __shared__ float xts[4][512];       //  8 KiB
    __shared__ float ylds[4][512];      //  8 KiB

    int s8 = lane >> 3;
    int j8 = lane & 7;

    // ---- prologue: xt full preload + ip chunks 0..2 ----
    GLL16(xtrow + lane * 4,       &xts[w][0]);
    GLL16(xtrow + 256 + lane * 4, &xts[w][256]);
#pragma unroll
    for (int k = 0; k < 3; ++k) {
        GLL16(ipb + k * 512 + lane * 4,       &ip[w][k][0][0]);
        GLL16(ipb + k * 512 + 256 + lane * 4, &ip[w][k][4][0]);
    }

    float h = 0.f;

#define CONSUME(CC, CS)                                                          \
    {                                                                            \
        float ipv_[8];                                                           \
        _Pragma("unroll")                                                        \
        for (int i_ = 0; i_ < 8; ++i_) ipv_[i_] = ip[w][CS][i_][lane];           \
        float4 xv0_ = *(const float4*)&xts[w][(CC) * 8];                         \
        float4 xv1_ = *(const float4*)&xts[w][(CC) * 8 + 4];                     \
        const float xs_[8] = {xv0_.x, xv0_.y, xv0_.z, xv0_.w,                    \
                              xv1_.x, xv1_.y, xv1_.z, xv1_.w};                   \
        _Pragma("unroll")                                                        \
        for (int i_ = 0; i_ < 8; ++i_) {                                         \
            h = __builtin_amdgcn_fmed3f(fmaf(h, a, ipv_[i_] * xs_[i_]), 0.f, 1.f); \
            ip[w][CS][i_][lane] = h * c;   /* in-place h*c for delayed reduce */ \
        }                                                                        \
    }
#define REDUCE(XX, PS)                                                           \
    {                                                                            \
        float4 v0_ = *(const float4*)&ip[w][PS][s8][j8 * 8];                     \
        float4 v1_ = *(const float4*)&ip[w][PS][s8][j8 * 8 + 4];                 \
        float s_ = ((v0_.x + v0_.y) + (v0_.z + v0_.w)) +                         \
                   ((v1_.x + v1_.y) + (v1_.z + v1_.w));                          \
        s_ = dppadd<0x111>(s_);                                                  \
        s_ = dppadd<0x112>(s_);                                                  \
        s_ = dppadd<0x114>(s_);                                                  \
        if (j8 == 7) ylds[w][(XX) * 8 + s8] = s_;                                \
    }
#define VWAIT                                           \
    asm volatile("s_waitcnt vmcnt(4)" ::: "memory");    \
    __builtin_amdgcn_sched_barrier(0);

    // ---- phase 0 (no reduce yet) ----
    {
        GLL16(ipb + 2 * 512 + lane * 4,       &ip[w][2][0][0]);  // dummy re-issue
        GLL16(ipb + 2 * 512 + 256 + lane * 4, &ip[w][2][4][0]);
        VWAIT
        CONSUME(0, 0)
    }
    // ---- phases 1..63 ----
    for (int cc = 1; cc < 64; ++cc) {
        int ch = cc + 2; if (ch > 63) ch = 63;       // clamped (keeps vmcnt const)
        int sl = (cc + 2) & 3;
        GLL16(ipb + ch * 512 + lane * 4,       &ip[w][sl][0][0]);
        GLL16(ipb + ch * 512 + 256 + lane * 4, &ip[w][sl][4][0]);
        VWAIT
        int cs = cc & 3;
        CONSUME(cc, cs)
        REDUCE(cc - 1, (cc - 1) & 3)
    }
    // ---- epilogue: reduce chunk 63, then write y out once (coalesced LDS read,
    // scattered global stores batched at the end, outside the vmcnt window) ----
    REDUCE(63, 3)
#pragma unroll
    for (int k = 0; k < 8; ++k) {
        float v = ylds[w][lane + k * 64];
        y_d[(size_t)(lane + k * 64) * DD] = v;
    }
    hfin[((size_t)b * DD + d) * NN + lane] = h;
}

// ---- fallback scan (no xT; strided x reads; tiled inpT layout) ----
__global__ __launch_bounds__(256) void scan_fb_kernel(const float* __restrict__ x,
                                                      const float* __restrict__ Araw,
                                                      const float* __restrict__ Craw,
                                                      const float* __restrict__ inpT,
                                                      float* __restrict__ Y,
                                                      float* __restrict__ hfin) {
    int wid  = (blockIdx.x * 256 + threadIdx.x) >> 6;
    int lane = threadIdx.x & 63;
    int b = wid / DD;
    int d = wid - b * DD;

    float a = sigmf(Araw[d * NN + lane]);
    float c = sigmf(Craw[d * NN + lane]);

    const float* ipb   = inpT + (size_t)b * 64 * 512;
    const float* x_ptr = x + (b * SS) * DD + d;
    float*       y_ptr = Y + (b * SS) * DD + d;

#define IPAT(T) ipb[(((T) >> 3) * 8 + ((T) & 7)) * 64 + lane]

    float cip[8], cxv[8], nip[8], nxv[8];
#pragma unroll
    for (int i = 0; i < 8; ++i) {
        cip[i] = IPAT(i);
        cxv[i] = x_ptr[i * DD];
    }
    float h = 0.f;
    for (int t0 = 0; t0 < SS; t0 += 8) {
        int tn = t0 + 8;
        if (tn >= SS) tn = SS - 8;
#pragma unroll
        for (int i = 0; i < 8; ++i) {
            nip[i] = IPAT(tn + i);
            nxv[i] = x_ptr[(tn + i) * DD];
        }
#pragma unroll
        for (int i = 0; i < 8; ++i) {
            h = __builtin_amdgcn_fmed3f(fmaf(h, a, cip[i] * cxv[i]), 0.f, 1.f);
            float v = wave_sum63(h * c);
            if (lane == 63) y_ptr[(t0 + i) * DD] = v;
        }
#pragma unroll
        for (int i = 0; i < 8; ++i) { cip[i] = nip[i]; cxv[i] = nxv[i]; }
    }
    hfin[(size_t)wid * NN + lane] = h;
}

// ---- phase 3: in-place layernorm + gamma + residual + clip (float4) ----
__global__ __launch_bounds__(256) void ln_kernel(const float* __restrict__ x,
                                                 const float* __restrict__ gamma_s,
                                                 float* __restrict__ out) {
    int wid  = (blockIdx.x * 256 + threadIdx.x) >> 6;
    int lane = threadIdx.x & 63;
    float*       yr = out + (size_t)wid * DD;
    const float* xr = x   + (size_t)wid * DD;

    float4 y0 = ((const float4*)yr)[lane * 3 + 0];
    float4 y1 = ((const float4*)yr)[lane * 3 + 1];
    float4 y2 = ((const float4*)yr)[lane * 3 + 2];

    float s = ((y0.x + y0.y) + (y0.z + y0.w)) + ((y1.x + y1.y) + (y1.z + y1.w)) +
              ((y2.x + y2.y) + (y2.z + y2.w));
#pragma unroll
    for (int off = 32; off; off >>= 1) s += __shfl_xor(s, off, 64);
    float mu = s * (1.f / 768.f);

    float q = 0.f;
#define QACC(v)                 \
    {                           \
        float d0_ = (v) - mu;   \
        q = fmaf(d0_, d0_, q);  \
    }
    QACC(y0.x) QACC(y0.y) QACC(y0.z) QACC(y0.w)
    QACC(y1.x) QACC(y1.y) QACC(y1.z) QACC(y1.w)
    QACC(y2.x) QACC(y2.y) QACC(y2.z) QACC(y2.w)
#pragma unroll
    for (int off = 32; off; off >>= 1) q += __shfl_xor(q, off, 64);
    float inv = rsqrtf(q * (1.f / 768.f) + 1e-5f);

    float4 g0 = ((const float4*)gamma_s)[lane * 3 + 0];
    float4 g1 = ((const float4*)gamma_s)[lane * 3 + 1];
    float4 g2 = ((const float4*)gamma_s)[lane * 3 + 2];
    float4 x0 = ((const float4*)xr)[lane * 3 + 0];
    float4 x1 = ((const float4*)xr)[lane * 3 + 1];
    float4 x2 = ((const float4*)xr)[lane * 3 + 2];

#define FIN(yv, gv, xv) __builtin_amdgcn_fmed3f(fmaf((yv - mu) * inv, gv, xv), 0.f, 1.f)
    float4 o0, o1, o2;
    o0.x = FIN(y0.x, g0.x, x0.x); o0.y = FIN(y0.y, g0.y, x0.y);
    o0.z = FIN(y0.z, g0.z, x0.z); o0.w = FIN(y0.w, g0.w, x0.w);
    o1.x = FIN(y1.x, g1.x, x1.x); o1.y = FIN(y1.y, g1.y, x1.y);
    o1.z = FIN(y1.z, g1.z, x1.z); o1.w = FIN(y1.w, g1.w, x1.w);
    o2.x = FIN(y2.x, g2.x, x2.x); o2.y = FIN(y2.y, g2.y, x2.y);
    o2.z = FIN(y2.z, g2.z, x2.z); o2.w = FIN(y2.w, g2.w, x2.w);

    ((float4*)yr)[lane * 3 + 0] = o0;
    ((float4*)yr)[lane * 3 + 1] = o1;
    ((float4*)yr)[lane * 3 + 2] = o2;
}

extern "C" void kernel_launch(void* const* d_in, const int* in_sizes, int n_in,
                              void* d_out, int out_size, void* d_ws, size_t ws_size,
                              hipStream_t stream) {
    const float* x    = (const float*)d_in[0];  // [B,S,D]
    const float* Araw = (const float*)d_in[1];  // [D,N]
    const float* Braw = (const float*)d_in[2];  // [N,D]
    const float* Craw = (const float*)d_in[3];  // [D,N]
    const float* graw = (const float*)d_in[4];  // [D]

    float* out  = (float*)d_out;                // [B,S,D] then [B,D,N]
    float* hfin = out + (size_t)BSD;

    float* ws      = (float*)d_ws;
    float* BwT     = ws;                                   // D*N   = 49152
    float* gamma_s = ws + DD * NN;                         // D     = 768
    float* inp     = ws + DD * NN + DD;                    // B*S*N = 131072 (tiled)
    float* xT      = ws + DD * NN + DD + BB * SS * NN;     // B*D*S = 1572864

    size_t need = (size_t)(DD * NN + DD + (size_t)BB * SS * NN + (size_t)BSD) * sizeof(float);

    if (ws_size >= need) {
        prep_xpose_kernel<<<12 + BB * (SS / 64) * (DD / 64), 256, 0, stream>>>(
            Braw, graw, x, BwT, gamma_s, xT);
        inp_kernel<<<(BB * SS) / 4, 256, 0, stream>>>(x, BwT, inp);
        scan_kernel<<<BB * (DD / 4), 256, 0, stream>>>(xT, Araw, Craw, inp, out, hfin);
    } else {
        prep_xpose_kernel<<<12, 256, 0, stream>>>(Braw, graw, x, BwT, gamma_s, xT);
        inp_kernel<<<(BB * SS) / 4, 256, 0, stream>>>(x, BwT, inp);
        scan_fb_kernel<<<(BB * DD * NN) / 256, 256, 0, stream>>>(x, Araw, Craw, inp, out, hfin);
    }
    ln_kernel<<<(BB * SS * NN) / 256, 256, 0, stream>>>(x, gamma_s, out);
}

// Round 20
// 61.282 us; speedup vs baseline: 1.2511x; 1.2511x over previous
//
#include <hip/hip_runtime.h>
#include <math.h>

#define DD 768
#define NN 64
#define SS 512
#define BB 4
#define BSD (BB * SS * DD)

__device__ __forceinline__ float sigmf(float v) { return 1.0f / (1.0f + expf(-v)); }

// ---- DPP add helper (bound_ctrl=0-fill) ----
template <int CTRL>
__device__ __forceinline__ float dppadd(float v) {
    int s = __builtin_amdgcn_update_dpp(0, __float_as_int(v), CTRL, 0xF, 0xF, true);
    return v + __int_as_float(s);
}
__device__ __forceinline__ float row_sum15(float v) {
    v = dppadd<0x111>(v);
    v = dppadd<0x112>(v);
    v = dppadd<0x114>(v);
    v = dppadd<0x118>(v);
    return v;
}
__device__ __forceinline__ float wave_sum63(float v) {
    v = row_sum15(v);
    v = dppadd<0x142>(v);
    v = dppadd<0x143>(v);
    return v;
}

// ---- prep: BwT[d][n] = sigmoid(Braw[n][d]) via LDS tile; gamma (12 blocks) ----
__global__ __launch_bounds__(256) void prep_kernel(const float* __restrict__ Braw,
                                                   const float* __restrict__ graw,
                                                   float* __restrict__ BwT,
                                                   float* __restrict__ gamma_s) {
    __shared__ float tile[64][65];
    int tx = threadIdx.x & 63;
    int tq = threadIdx.x >> 6;
    int d0 = blockIdx.x * 64;
#pragma unroll
    for (int i = 0; i < 16; ++i) {
        int n = tq + i * 4;
        tile[n][tx] = sigmf(Braw[n * DD + d0 + tx]);
    }
    __syncthreads();
#pragma unroll
    for (int i = 0; i < 16; ++i) {
        int dl = tq + i * 4;
        BwT[(d0 + dl) * NN + tx] = tile[tx][dl];
    }
    int gi = blockIdx.x * 256 + threadIdx.x;
    if (gi < DD) gamma_s[gi] = sigmf(graw[gi]);
}

// ---- fused: blocks 0..511 = inp (LDS-staged BwT, linear store);
//      blocks 512..895 = x-transpose tiles. Independent work, overlapped. ----
__global__ __launch_bounds__(256, 2) void inp_xpose_kernel(const float* __restrict__ x,
                                                           const float* __restrict__ BwT,
                                                           float* __restrict__ inp,
                                                           float* __restrict__ xT) {
    __shared__ float4 smem[2048];   // 32 KiB: bwlds[2][1024] OR tile[64][65] view

    if (blockIdx.x < 512) {
        float4* bwlds0 = smem;            // [1024]
        float4* bwlds1 = smem + 1024;     // [1024]
        int w    = threadIdx.x >> 6;
        int lane = threadIdx.x & 63;
        int g = lane >> 4;
        int q = lane & 15;
        int r = blockIdx.x * 4 + w;
        const float*  xr  = x + (size_t)r * DD;
        const float4* bwg = (const float4*)BwT;

#pragma unroll
        for (int k = 0; k < 4; ++k)
            bwlds0[threadIdx.x + k * 256] = bwg[threadIdx.x + k * 256];
        __syncthreads();

        float4 acc = {0.f, 0.f, 0.f, 0.f};
        for (int c = 0; c < 12; ++c) {
            float4* cur = (c & 1) ? bwlds1 : bwlds0;
            float4* nxt = (c & 1) ? bwlds0 : bwlds1;
            float4 s0, s1, s2, s3;
            if (c < 11) {
                int base = (c + 1) * 1024 + threadIdx.x;
                s0 = bwg[base];
                s1 = bwg[base + 256];
                s2 = bwg[base + 512];
                s3 = bwg[base + 768];
            }
            int d0 = c * 64;
#pragma unroll
            for (int jj = 0; jj < 4; ++jj) {
                int dbase = jj * 16 + g;
                float x0 = xr[d0 + dbase + 0];
                float x1 = xr[d0 + dbase + 4];
                float x2 = xr[d0 + dbase + 8];
                float x3 = xr[d0 + dbase + 12];
                float4 w0 = cur[(dbase + 0) * 16 + q];
                float4 w1 = cur[(dbase + 4) * 16 + q];
                float4 w2 = cur[(dbase + 8) * 16 + q];
                float4 w3 = cur[(dbase + 12) * 16 + q];
#define IFMA(W, X)                       \
    acc.x = fmaf(X, W.x, acc.x);         \
    acc.y = fmaf(X, W.y, acc.y);         \
    acc.z = fmaf(X, W.z, acc.z);         \
    acc.w = fmaf(X, W.w, acc.w);
                IFMA(w0, x0) IFMA(w1, x1) IFMA(w2, x2) IFMA(w3, x3)
            }
            if (c < 11) {
                nxt[threadIdx.x]       = s0;
                nxt[threadIdx.x + 256] = s1;
                nxt[threadIdx.x + 512] = s2;
                nxt[threadIdx.x + 768] = s3;
            }
            __syncthreads();
        }

#pragma unroll
        for (int off = 16; off <= 32; off <<= 1) {
            acc.x += __shfl_xor(acc.x, off, 64);
            acc.y += __shfl_xor(acc.y, off, 64);
            acc.z += __shfl_xor(acc.z, off, 64);
            acc.w += __shfl_xor(acc.w, off, 64);
        }
        if (lane < 16) ((float4*)(inp + (size_t)r * NN))[q] = acc;
    } else {
        float* tile = (float*)smem;   // [64][65] view (16.6 KiB of the 32)
        int bidx = blockIdx.x - 512;  // 0..383
        int b  = bidx / 96;
        int r  = bidx - b * 96;
        int t0 = (r / 12) * 64;
        int d0 = (r % 12) * 64;
        int tx = threadIdx.x & 63;
        int tq = threadIdx.x >> 6;
#pragma unroll
        for (int i = 0; i < 16; ++i) {
            int t = tq + i * 4;
            tile[t * 65 + tx] = x[((size_t)b * SS + t0 + t) * DD + d0 + tx];
        }
        __syncthreads();
#pragma unroll
        for (int i = 0; i < 16; ++i) {
            int dl = tq + i * 4;
            xT[((size_t)b * DD + d0 + dl) * SS + t0 + tx] = tile[tx * 65 + dl];
        }
    }
}

// ---- phase 2: scan v15 = v9 (R13: 4 rotating SCALAR buffers, register
// consume — the only prefetch form the compiler provably keeps, R9 VGPR=32)
// + LDS used ONLY for the h*c transpose reduce (4KB/chunk vs v12's 8KB:
// halves LDS-pipe load) + rows padded 64->68 (8-way -> 2-way on b128 read).
__global__ __launch_bounds__(256, 3) void scan_kernel(const float* __restrict__ xT,
                                                      const float* __restrict__ Araw,
                                                      const float* __restrict__ Craw,
                                                      const float* __restrict__ inp,
                                                      float* __restrict__ Y,
                                                      float* __restrict__ hfin) {
    int w    = threadIdx.x >> 6;        // wave in block = d-sub
    int lane = threadIdx.x & 63;        // n
    int gb = blockIdx.x;                // 0..767
    int b  = gb / 192;
    int dg = gb - b * 192;
    int d  = dg * 4 + w;

    float a = sigmf(Araw[(size_t)d * NN + lane]);
    float c = sigmf(Craw[(size_t)d * NN + lane]);

    const float*  ip_ptr = inp + (size_t)(b * SS) * NN + lane;   // 256B coalesced
    const float4* xt4    = (const float4*)(xT + ((size_t)b * DD + d) * SS);
    float*        y_d    = Y + (size_t)(b * SS) * DD + d;

    __shared__ float lds[4][2][8][68];  // [wave][slab][step][n pad68] = 17.4 KiB

    int s8 = lane >> 3;
    int j8 = lane & 7;

    float Ai[8], Bi[8], Ci[8], Di[8];
    float4 Ax0, Ax1, Bx0, Bx1, Cx0, Cx1, Dx0, Dx1;
    float h = 0.f;

#define SPREF(P, T0)                                                       \
    {                                                                      \
        int tt_ = ((T0) < SS) ? (T0) : 0;                                  \
        _Pragma("unroll")                                                  \
        for (int i_ = 0; i_ < 8; ++i_) P##i[i_] = ip_ptr[(tt_ + i_) * NN]; \
        P##x0 = xt4[(tt_ >> 2) + 0];                                       \
        P##x1 = xt4[(tt_ >> 2) + 1];                                       \
    }
#define SCHUNK(P, T0, SL)                                                         \
    {                                                                             \
        const float xs_[8] = {P##x0.x, P##x0.y, P##x0.z, P##x0.w,                 \
                              P##x1.x, P##x1.y, P##x1.z, P##x1.w};                \
        _Pragma("unroll")                                                         \
        for (int i_ = 0; i_ < 8; ++i_) {                                          \
            h = __builtin_amdgcn_fmed3f(fmaf(h, a, P##i[i_] * xs_[i_]), 0.f, 1.f); \
            lds[w][SL][i_][lane] = h * c;                                         \
        }                                                                         \
        float4 v0_ = *(const float4*)&lds[w][SL][s8][j8 * 8];                     \
        float4 v1_ = *(const float4*)&lds[w][SL][s8][j8 * 8 + 4];                 \
        float s_ = ((v0_.x + v0_.y) + (v0_.z + v0_.w)) +                          \
                   ((v1_.x + v1_.y) + (v1_.z + v1_.w));                           \
        s_ = dppadd<0x111>(s_);                                                   \
        s_ = dppadd<0x112>(s_);                                                   \
        s_ = dppadd<0x114>(s_);                                                   \
        if (j8 == 7) y_d[((T0) + s8) * DD] = s_;                                  \
    }

    SPREF(A, 0)
    SPREF(B, 8)
    SPREF(C, 16)
    SPREF(D, 24)

    for (int t0 = 0; t0 < SS; t0 += 32) {
        SCHUNK(A, t0, 0)      SPREF(A, t0 + 32)
        SCHUNK(B, t0 + 8, 1)  SPREF(B, t0 + 40)
        SCHUNK(C, t0 + 16, 0) SPREF(C, t0 + 48)
        SCHUNK(D, t0 + 24, 1) SPREF(D, t0 + 56)
    }
    hfin[((size_t)b * DD + d) * NN + lane] = h;
}

// ---- fallback scan (no xT; strided x reads; linear inp) ----
__global__ __launch_bounds__(256) void scan_fb_kernel(const float* __restrict__ x,
                                                      const float* __restrict__ Araw,
                                                      const float* __restrict__ Craw,
                                                      const float* __restrict__ inp,
                                                      float* __restrict__ Y,
                                                      float* __restrict__ hfin) {
    int wid  = (blockIdx.x * 256 + threadIdx.x) >> 6;
    int lane = threadIdx.x & 63;
    int b = wid / DD;
    int d = wid - b * DD;

    float a = sigmf(Araw[d * NN + lane]);
    float c = sigmf(Craw[d * NN + lane]);

    const float* ip_ptr = inp + (b * SS) * NN + lane;
    const float* x_ptr  = x   + (b * SS) * DD + d;
    float*       y_ptr  = Y   + (b * SS) * DD + d;

    float cip[8], cxv[8], nip[8], nxv[8];
#pragma unroll
    for (int i = 0; i < 8; ++i) {
        cip[i] = ip_ptr[i * NN];
        cxv[i] = x_ptr[i * DD];
    }
    float h = 0.f;
    for (int t0 = 0; t0 < SS; t0 += 8) {
        int tn = t0 + 8;
        if (tn >= SS) tn = SS - 8;
#pragma unroll
        for (int i = 0; i < 8; ++i) {
            nip[i] = ip_ptr[(tn + i) * NN];
            nxv[i] = x_ptr[(tn + i) * DD];
        }
#pragma unroll
        for (int i = 0; i < 8; ++i) {
            h = __builtin_amdgcn_fmed3f(fmaf(h, a, cip[i] * cxv[i]), 0.f, 1.f);
            float v = wave_sum63(h * c);
            if (lane == 63) y_ptr[(t0 + i) * DD] = v;
        }
#pragma unroll
        for (int i = 0; i < 8; ++i) { cip[i] = nip[i]; cxv[i] = nxv[i]; }
    }
    hfin[(size_t)wid * NN + lane] = h;
}

// ---- phase 3: in-place layernorm + gamma + residual + clip (float4) ----
__global__ __launch_bounds__(256) void ln_kernel(const float* __restrict__ x,
                                                 const float* __restrict__ gamma_s,
                                                 float* __restrict__ out) {
    int wid  = (blockIdx.x * 256 + threadIdx.x) >> 6;
    int lane = threadIdx.x & 63;
    float*       yr = out + (size_t)wid * DD;
    const float* xr = x   + (size_t)wid * DD;

    float4 y0 = ((const float4*)yr)[lane * 3 + 0];
    float4 y1 = ((const float4*)yr)[lane * 3 + 1];
    float4 y2 = ((const float4*)yr)[lane * 3 + 2];

    float s = ((y0.x + y0.y) + (y0.z + y0.w)) + ((y1.x + y1.y) + (y1.z + y1.w)) +
              ((y2.x + y2.y) + (y2.z + y2.w));
#pragma unroll
    for (int off = 32; off; off >>= 1) s += __shfl_xor(s, off, 64);
    float mu = s * (1.f / 768.f);

    float q = 0.f;
#define QACC(v)                 \
    {                           \
        float d0_ = (v) - mu;   \
        q = fmaf(d0_, d0_, q);  \
    }
    QACC(y0.x) QACC(y0.y) QACC(y0.z) QACC(y0.w)
    QACC(y1.x) QACC(y1.y) QACC(y1.z) QACC(y1.w)
    QACC(y2.x) QACC(y2.y) QACC(y2.z) QACC(y2.w)
#pragma unroll
    for (int off = 32; off; off >>= 1) q += __shfl_xor(q, off, 64);
    float inv = rsqrtf(q * (1.f / 768.f) + 1e-5f);

    float4 g0 = ((const float4*)gamma_s)[lane * 3 + 0];
    float4 g1 = ((const float4*)gamma_s)[lane * 3 + 1];
    float4 g2 = ((const float4*)gamma_s)[lane * 3 + 2];
    float4 x0 = ((const float4*)xr)[lane * 3 + 0];
    float4 x1 = ((const float4*)xr)[lane * 3 + 1];
    float4 x2 = ((const float4*)xr)[lane * 3 + 2];

#define FIN(yv, gv, xv) __builtin_amdgcn_fmed3f(fmaf((yv - mu) * inv, gv, xv), 0.f, 1.f)
    float4 o0, o1, o2;
    o0.x = FIN(y0.x, g0.x, x0.x); o0.y = FIN(y0.y, g0.y, x0.y);
    o0.z = FIN(y0.z, g0.z, x0.z); o0.w = FIN(y0.w, g0.w, x0.w);
    o1.x = FIN(y1.x, g1.x, x1.x); o1.y = FIN(y1.y, g1.y, x1.y);
    o1.z = FIN(y1.z, g1.z, x1.z); o1.w = FIN(y1.w, g1.w, x1.w);
    o2.x = FIN(y2.x, g2.x, x2.x); o2.y = FIN(y2.y, g2.y, x2.y);
    o2.z = FIN(y2.z, g2.z, x2.z); o2.w = FIN(y2.w, g2.w, x2.w);

    ((float4*)yr)[lane * 3 + 0] = o0;
    ((float4*)yr)[lane * 3 + 1] = o1;
    ((float4*)yr)[lane * 3 + 2] = o2;
}

extern "C" void kernel_launch(void* const* d_in, const int* in_sizes, int n_in,
                              void* d_out, int out_size, void* d_ws, size_t ws_size,
                              hipStream_t stream) {
    const float* x    = (const float*)d_in[0];  // [B,S,D]
    const float* Araw = (const float*)d_in[1];  // [D,N]
    const float* Braw = (const float*)d_in[2];  // [N,D]
    const float* Craw = (const float*)d_in[3];  // [D,N]
    const float* graw = (const float*)d_in[4];  // [D]

    float* out  = (float*)d_out;                // [B,S,D] then [B,D,N]
    float* hfin = out + (size_t)BSD;

    float* ws      = (float*)d_ws;
    float* BwT     = ws;                                   // D*N   = 49152
    float* gamma_s = ws + DD * NN;                         // D     = 768
    float* inp     = ws + DD * NN + DD;                    // B*S*N = 131072
    float* xT      = ws + DD * NN + DD + BB * SS * NN;     // B*D*S = 1572864

    size_t need = (size_t)(DD * NN + DD + (size_t)BB * SS * NN + (size_t)BSD) * sizeof(float);

    if (ws_size >= need) {
        prep_kernel<<<DD / 64, 256, 0, stream>>>(Braw, graw, BwT, gamma_s);
        // fused: 512 inp blocks + 384 xpose blocks, concurrent
        inp_xpose_kernel<<<512 + BB * (SS / 64) * (DD / 64), 256, 0, stream>>>(
            x, BwT, inp, xT);
        scan_kernel<<<BB * (DD / 4), 256, 0, stream>>>(xT, Araw, Craw, inp, out, hfin);
    } else {
        prep_kernel<<<DD / 64, 256, 0, stream>>>(Braw, graw, BwT, gamma_s);
        inp_xpose_kernel<<<512 + BB * (SS / 64) * (DD / 64), 256, 0, stream>>>(
            x, BwT, inp, xT);
        scan_fb_kernel<<<(BB * DD * NN) / 256, 256, 0, stream>>>(x, Araw, Craw, inp, out, hfin);
    }
    ln_kernel<<<(BB * SS * NN) / 256, 256, 0, stream>>>(x, gamma_s, out);
}